// Round 1
// baseline (648.539 us; speedup 1.0000x reference)
//
#include <hip/hip_runtime.h>
#include <cstdint>

typedef __bf16 bf16;
typedef bf16 bf16x8 __attribute__((ext_vector_type(8)));
typedef bf16 bf16x4 __attribute__((ext_vector_type(4)));
typedef float f32x4 __attribute__((ext_vector_type(4)));
typedef uint32_t u32;

static constexpr int E_ = 1024;
static constexpr int H_ = 16;
static constexpr int DH_ = 64;
static constexpr int F_ = 4096;
static constexpr int B_ = 4;
static constexpr int S_ = 1024;
static constexpr long TOK = (long)B_ * S_;  // 4096 tokens

__device__ static __forceinline__ void gld16(const void* g, void* l) {
  __builtin_amdgcn_global_load_lds(
      (const __attribute__((address_space(1))) u32*)g,
      (__attribute__((address_space(3))) u32*)l, 16, 0, 0);
}

__device__ __forceinline__ f32x4 mfma16(bf16x8 a, bf16x8 b, f32x4 c) {
  return __builtin_amdgcn_mfma_f32_16x16x32_bf16(a, b, c, 0, 0, 0);
}

// ---------------------------------------------------------------- f32 -> bf16
__global__ __launch_bounds__(256) void f2b_kernel(const float* __restrict__ in,
                                                  bf16* __restrict__ out, int n8) {
  int v = blockIdx.x * 256 + threadIdx.x;
  if (v >= n8) return;
  const float4* p = (const float4*)in + (long)v * 2;
  float4 a = p[0], b = p[1];
  bf16x8 o = {(bf16)a.x, (bf16)a.y, (bf16)a.z, (bf16)a.w,
              (bf16)b.x, (bf16)b.y, (bf16)b.z, (bf16)b.w};
  *((bf16x8*)out + v) = o;
}

// ---------------------------------------------------------------- GEMM (NT)
// C[M,N] = A[M,K] * B[N,K]^T, bf16 inputs, m97-style global_load_lds staging.
// 128x128 tile, BK=64, 4 waves each 64x64. LDS unpadded (required by gld16).
enum { EPI_BIAS_F32 = 0, EPI_BIAS_RELU_BF16 = 1, EPI_QKV = 2, EPI_BIAS_RES_F32 = 3 };

template <int EPI>
__global__ __launch_bounds__(256, 2) void gemm_nt(
    const bf16* __restrict__ A, const bf16* __restrict__ Bm,
    float* __restrict__ Cf, bf16* __restrict__ Cb,
    bf16* __restrict__ Qh, bf16* __restrict__ Kh, bf16* __restrict__ Vt,
    const float* __restrict__ bias, const float* __restrict__ res,
    int K, int ldc) {
  __shared__ bf16 As[128 * 64];
  __shared__ bf16 Bs[128 * 64];
  const int tid = threadIdx.x, lane = tid & 63, wave = tid >> 6;
  const int quad = lane >> 4, l16 = lane & 15;
  const int wm = wave >> 1, wn = wave & 1;
  const int row0 = blockIdx.y * 128, col0 = blockIdx.x * 128;

  const long ldab = (long)K * 2;  // bytes per input row
  const char* Ag = (const char*)A +
                   (long)(row0 + wave * 32 + (lane >> 3)) * ldab + (lane & 7) * 16;
  const char* Bg = (const char*)Bm +
                   (long)(col0 + wave * 32 + (lane >> 3)) * ldab + (lane & 7) * 16;
  char* Al = (char*)As + wave * 4096 + lane * 16;
  char* Bl = (char*)Bs + wave * 4096 + lane * 16;

  f32x4 acc[4][4];
#pragma unroll
  for (int i = 0; i < 4; i++)
#pragma unroll
    for (int j = 0; j < 4; j++) acc[i][j] = (f32x4){0.f, 0.f, 0.f, 0.f};

  for (int k0 = 0; k0 < K; k0 += 64) {
    __syncthreads();
#pragma unroll
    for (int c = 0; c < 4; c++) gld16(Ag + (long)c * 8 * ldab + k0 * 2, Al + c * 1024);
#pragma unroll
    for (int c = 0; c < 4; c++) gld16(Bg + (long)c * 8 * ldab + k0 * 2, Bl + c * 1024);
    __syncthreads();
#pragma unroll
    for (int kk = 0; kk < 2; kk++) {
      bf16x8 af[4], bfr[4];
#pragma unroll
      for (int i = 0; i < 4; i++)
        af[i] = *(const bf16x8*)&As[(wm * 64 + i * 16 + l16) * 64 + kk * 32 + quad * 8];
#pragma unroll
      for (int j = 0; j < 4; j++)
        bfr[j] = *(const bf16x8*)&Bs[(wn * 64 + j * 16 + l16) * 64 + kk * 32 + quad * 8];
#pragma unroll
      for (int i = 0; i < 4; i++)
#pragma unroll
        for (int j = 0; j < 4; j++) acc[i][j] = mfma16(af[i], bfr[j], acc[i][j]);
    }
  }

#pragma unroll
  for (int i = 0; i < 4; i++)
#pragma unroll
    for (int j = 0; j < 4; j++)
#pragma unroll
      for (int r = 0; r < 4; r++) {
        int row = row0 + wm * 64 + i * 16 + quad * 4 + r;
        int col = col0 + wn * 64 + j * 16 + l16;
        float v = acc[i][j][r];
        if constexpr (EPI == EPI_BIAS_F32) {
          Cf[(long)row * ldc + col] = v + bias[col];
        } else if constexpr (EPI == EPI_BIAS_RES_F32) {
          Cf[(long)row * ldc + col] = v + bias[col] + res[(long)row * ldc + col];
        } else if constexpr (EPI == EPI_BIAS_RELU_BF16) {
          Cb[(long)row * ldc + col] = (bf16)fmaxf(v + bias[col], 0.f);
        } else {  // EPI_QKV scatter
          float t = v + bias[col];
          int b_ = row >> 10, s_ = row & 1023;
          int which = col >> 10, nn = col & 1023;
          int h_ = nn >> 6, d_ = nn & 63;
          if (which == 2) {
            Vt[(((long)(b_ * H_ + h_)) * DH_ + d_) * S_ + s_] = (bf16)t;
          } else {
            long q = (((long)(b_ * H_ + h_)) * S_ + s_) * DH_ + d_;
            if (which == 0) Qh[q] = (bf16)t;
            else Kh[q] = (bf16)t;
          }
        }
      }
}

// --------------------------------------------------- fused attention, pass 1
// rowsum[bh, q] = sum_k exp(q.k*scale + mask)  (no max subtraction; scores
// are bounded ~|2.5| for this problem -> fp32-safe).
__global__ __launch_bounds__(256, 2) void attn_pass1(
    const bf16* __restrict__ Q, const bf16* __restrict__ K,
    const float* __restrict__ mask, float* __restrict__ rowsum) {
  __shared__ bf16 Qs[128 * 64];
  __shared__ bf16 Ks[128 * 64];
  const int tid = threadIdx.x, lane = tid & 63, wave = tid >> 6;
  const int quad = lane >> 4, l16 = lane & 15;
  const int q0 = blockIdx.x * 128, bh = blockIdx.y;
  const bf16* Qb = Q + ((long)bh * S_ + q0) * DH_;
  const bf16* Kb = K + (long)bh * S_ * DH_;

  {  // Q tile is contiguous 16 KB
    const char* g = (const char*)Qb + wave * 4096 + lane * 16;
    char* l = (char*)Qs + wave * 4096 + lane * 16;
#pragma unroll
    for (int c = 0; c < 4; c++) gld16(g + c * 1024, l + c * 1024);
  }

  float rs[2][4];
#pragma unroll
  for (int i = 0; i < 2; i++)
#pragma unroll
    for (int r = 0; r < 4; r++) rs[i][r] = 0.f;

  for (int t = 0; t < 8; t++) {
    __syncthreads();
    {
      const char* g = (const char*)Kb + (long)t * 16384 + wave * 4096 + lane * 16;
      char* l = (char*)Ks + wave * 4096 + lane * 16;
#pragma unroll
      for (int c = 0; c < 4; c++) gld16(g + c * 1024, l + c * 1024);
    }
    __syncthreads();
    f32x4 acc[2][8];
#pragma unroll
    for (int i = 0; i < 2; i++)
#pragma unroll
      for (int j = 0; j < 8; j++) acc[i][j] = (f32x4){0.f, 0.f, 0.f, 0.f};
#pragma unroll
    for (int kk = 0; kk < 2; kk++) {
      bf16x8 af[2], bfr[8];
#pragma unroll
      for (int i = 0; i < 2; i++)
        af[i] = *(const bf16x8*)&Qs[(wave * 32 + i * 16 + l16) * 64 + kk * 32 + quad * 8];
#pragma unroll
      for (int j = 0; j < 8; j++)
        bfr[j] = *(const bf16x8*)&Ks[(j * 16 + l16) * 64 + kk * 32 + quad * 8];
#pragma unroll
      for (int i = 0; i < 2; i++)
#pragma unroll
        for (int j = 0; j < 8; j++) acc[i][j] = mfma16(af[i], bfr[j], acc[i][j]);
    }
#pragma unroll
    for (int i = 0; i < 2; i++)
#pragma unroll
      for (int j = 0; j < 8; j++)
#pragma unroll
        for (int r = 0; r < 4; r++) {
          int qr = q0 + wave * 32 + i * 16 + quad * 4 + r;
          int gcol = t * 128 + j * 16 + l16;
          float sv = acc[i][j][r] * 0.125f + mask[(long)qr * S_ + gcol];
          rs[i][r] += __expf(sv);
        }
  }
#pragma unroll
  for (int i = 0; i < 2; i++)
#pragma unroll
    for (int r = 0; r < 4; r++) {
      float v = rs[i][r];
      v += __shfl_xor(v, 1);
      v += __shfl_xor(v, 2);
      v += __shfl_xor(v, 4);
      v += __shfl_xor(v, 8);
      if (l16 == 0)
        rowsum[(long)bh * S_ + q0 + wave * 32 + i * 16 + quad * 4 + r] = v;
    }
}

// --------------------------------------------------- fused attention, pass 2
// Recompute scores, normalize with rowsum, write W (fp32, output 1) once with
// NONTEMPORAL stores (268 MB stream, never re-read -> don't thrash L2),
// LDS round-trip P (C-layout -> A-layout), MFMA with V^T from global.
__global__ __launch_bounds__(256, 2) void attn_pass2(
    const bf16* __restrict__ Q, const bf16* __restrict__ K,
    const bf16* __restrict__ V, const float* __restrict__ mask,
    const float* __restrict__ rowsum, float* __restrict__ W,
    bf16* __restrict__ ctxb) {
  __shared__ bf16 Qs[128 * 64];
  __shared__ bf16 Ks[128 * 64];
  __shared__ bf16 Ps[128 * 136];  // +8 pad: 2-way-only read conflicts
  const int tid = threadIdx.x, lane = tid & 63, wave = tid >> 6;
  const int quad = lane >> 4, l16 = lane & 15;
  const int q0 = blockIdx.x * 128, bh = blockIdx.y;
  const bf16* Qb = Q + ((long)bh * S_ + q0) * DH_;
  const bf16* Kb = K + (long)bh * S_ * DH_;
  const bf16* Vb = V + (long)bh * DH_ * S_;

  float rinv[2][4];
#pragma unroll
  for (int i = 0; i < 2; i++)
#pragma unroll
    for (int r = 0; r < 4; r++)
      rinv[i][r] =
          1.0f / rowsum[(long)bh * S_ + q0 + wave * 32 + i * 16 + quad * 4 + r];

  {
    const char* g = (const char*)Qb + wave * 4096 + lane * 16;
    char* l = (char*)Qs + wave * 4096 + lane * 16;
#pragma unroll
    for (int c = 0; c < 4; c++) gld16(g + c * 1024, l + c * 1024);
  }

  f32x4 cacc[2][4];
#pragma unroll
  for (int i = 0; i < 2; i++)
#pragma unroll
    for (int j = 0; j < 4; j++) cacc[i][j] = (f32x4){0.f, 0.f, 0.f, 0.f};

  for (int t = 0; t < 8; t++) {
    __syncthreads();
    {
      const char* g = (const char*)Kb + (long)t * 16384 + wave * 4096 + lane * 16;
      char* l = (char*)Ks + wave * 4096 + lane * 16;
#pragma unroll
      for (int c = 0; c < 4; c++) gld16(g + c * 1024, l + c * 1024);
    }
    __syncthreads();
    f32x4 acc[2][8];
#pragma unroll
    for (int i = 0; i < 2; i++)
#pragma unroll
      for (int j = 0; j < 8; j++) acc[i][j] = (f32x4){0.f, 0.f, 0.f, 0.f};
#pragma unroll
    for (int kk = 0; kk < 2; kk++) {
      bf16x8 af[2], bfr[8];
#pragma unroll
      for (int i = 0; i < 2; i++)
        af[i] = *(const bf16x8*)&Qs[(wave * 32 + i * 16 + l16) * 64 + kk * 32 + quad * 8];
#pragma unroll
      for (int j = 0; j < 8; j++)
        bfr[j] = *(const bf16x8*)&Ks[(j * 16 + l16) * 64 + kk * 32 + quad * 8];
#pragma unroll
      for (int i = 0; i < 2; i++)
#pragma unroll
        for (int j = 0; j < 8; j++) acc[i][j] = mfma16(af[i], bfr[j], acc[i][j]);
    }
    // exp, normalize, emit W + P
#pragma unroll
    for (int i = 0; i < 2; i++)
#pragma unroll
      for (int j = 0; j < 8; j++)
#pragma unroll
        for (int r = 0; r < 4; r++) {
          int ql = wave * 32 + i * 16 + quad * 4 + r;
          int qr = q0 + ql;
          int col = j * 16 + l16, gcol = t * 128 + col;
          float u = __expf(acc[i][j][r] * 0.125f + mask[(long)qr * S_ + gcol]) *
                    rinv[i][r];
          __builtin_nontemporal_store(u, &W[((long)bh * S_ + qr) * S_ + gcol]);
          Ps[ql * 136 + col] = (bf16)u;
        }
    __syncthreads();  // P visible (cross-lane within wave; be safe)
    // PV: ctx += P(128xk128) * Vt(64xk128)^T
#pragma unroll
    for (int kk = 0; kk < 4; kk++) {
      bf16x8 pf[2], vf[4];
#pragma unroll
      for (int i = 0; i < 2; i++)
        pf[i] = *(const bf16x8*)&Ps[(wave * 32 + i * 16 + l16) * 136 + kk * 32 + quad * 8];
#pragma unroll
      for (int j = 0; j < 4; j++)
        vf[j] = *(const bf16x8*)(Vb + (long)(j * 16 + l16) * S_ + t * 128 +
                                 kk * 32 + quad * 8);
#pragma unroll
      for (int i = 0; i < 2; i++)
#pragma unroll
        for (int j = 0; j < 4; j++) cacc[i][j] = mfma16(pf[i], vf[j], cacc[i][j]);
    }
  }
  const int b_ = bh >> 4, h_ = bh & 15;
#pragma unroll
  for (int i = 0; i < 2; i++)
#pragma unroll
    for (int j = 0; j < 4; j++)
#pragma unroll
      for (int r = 0; r < 4; r++) {
        int qr = q0 + wave * 32 + i * 16 + quad * 4 + r;
        ctxb[((long)b_ * S_ + qr) * E_ + h_ * 64 + j * 16 + l16] =
            (bf16)cacc[i][j][r];
      }
}

// ------------------------------------------------------- layernorm (single in)
// Residual add is fused into the producing GEMM's epilogue (EPI_BIAS_RES_F32),
// so this reads ONE fp32 stream.
__global__ __launch_bounds__(256) void ln_kernel(
    const float* __restrict__ a, const float* __restrict__ g,
    const float* __restrict__ beta, float* __restrict__ outf,
    bf16* __restrict__ outb) {
  const int tid = threadIdx.x;
  const int wave = tid >> 6, lane = tid & 63;
  long base = (long)blockIdx.x * E_ + tid * 4;
  float4 x = *(const float4*)(a + base);
  float s = x.x + x.y + x.z + x.w;
  float sq = x.x * x.x + x.y * x.y + x.z * x.z + x.w * x.w;
#pragma unroll
  for (int o = 32; o; o >>= 1) { s += __shfl_xor(s, o); sq += __shfl_xor(sq, o); }
  __shared__ float rs[4], rq[4];
  if (!lane) { rs[wave] = s; rq[wave] = sq; }
  __syncthreads();
  s = rs[0] + rs[1] + rs[2] + rs[3];
  sq = rq[0] + rq[1] + rq[2] + rq[3];
  float mu = s * (1.f / E_);
  float var = sq * (1.f / E_) - mu * mu;
  float rstd = rsqrtf(var + 1e-5f);
  int c = tid * 4;
  float4 gg = *(const float4*)(g + c);
  float4 bb = *(const float4*)(beta + c);
  float o0 = (x.x - mu) * rstd * gg.x + bb.x;
  float o1 = (x.y - mu) * rstd * gg.y + bb.y;
  float o2 = (x.z - mu) * rstd * gg.z + bb.z;
  float o3 = (x.w - mu) * rstd * gg.w + bb.w;
  if (outf) *(float4*)(outf + base) = make_float4(o0, o1, o2, o3);
  if (outb) {
    bf16x4 ob = {(bf16)o0, (bf16)o1, (bf16)o2, (bf16)o3};
    *(bf16x4*)(outb + base) = ob;
  }
}

// ---------------------------------------------------------------- launch
extern "C" void kernel_launch(void* const* d_in, const int* in_sizes, int n_in,
                              void* d_out, int out_size, void* d_ws, size_t ws_size,
                              hipStream_t stream) {
  const float* src   = (const float*)d_in[0];
  const float* mask  = (const float*)d_in[1];
  const float* w_qkv = (const float*)d_in[2];
  const float* b_qkv = (const float*)d_in[3];
  const float* w_o   = (const float*)d_in[4];
  const float* b_o   = (const float*)d_in[5];
  const float* w1    = (const float*)d_in[6];
  const float* b1    = (const float*)d_in[7];
  const float* w2    = (const float*)d_in[8];
  const float* b2    = (const float*)d_in[9];
  const float* ln1g  = (const float*)d_in[10];
  const float* ln1b  = (const float*)d_in[11];
  const float* ln2g  = (const float*)d_in[12];
  const float* ln2b  = (const float*)d_in[13];

  float* out = (float*)d_out;
  float* attnW = out + TOK * E_;  // [B,H,S,S] fp32 (output 1)

  char* w = (char*)d_ws;
  auto alloc = [&](size_t bytes) {
    void* p = w;
    w += (bytes + 255) & ~(size_t)255;
    return p;
  };
  bf16* srcb  = (bf16*)alloc(TOK * E_ * 2);
  bf16* wqkvb = (bf16*)alloc((size_t)3 * E_ * E_ * 2);
  bf16* wob   = (bf16*)alloc((size_t)E_ * E_ * 2);
  bf16* w1b   = (bf16*)alloc((size_t)F_ * E_ * 2);
  bf16* w2b   = (bf16*)alloc((size_t)E_ * F_ * 2);
  bf16* Qh    = (bf16*)alloc((size_t)B_ * H_ * S_ * DH_ * 2);
  bf16* Kh    = (bf16*)alloc((size_t)B_ * H_ * S_ * DH_ * 2);
  bf16* Vt    = (bf16*)alloc((size_t)B_ * H_ * DH_ * S_ * 2);
  bf16* ctxb  = (bf16*)alloc(TOK * E_ * 2);
  float* attn_out = (float*)alloc(TOK * E_ * 4);
  float* x1f  = (float*)alloc(TOK * E_ * 4);
  bf16* x1b   = (bf16*)alloc(TOK * E_ * 2);
  bf16* h1b   = (bf16*)alloc(TOK * (size_t)F_ * 2);
  float* ffn2 = (float*)alloc(TOK * E_ * 4);
  float* rowsum = (float*)alloc((size_t)B_ * H_ * S_ * 4);

  auto f2b = [&](const float* in, bf16* o, long n) {
    int n8 = (int)(n / 8);
    f2b_kernel<<<(n8 + 255) / 256, 256, 0, stream>>>(in, o, n8);
  };
  f2b(src, srcb, TOK * E_);
  f2b(w_qkv, wqkvb, (long)3 * E_ * E_);
  f2b(w_o, wob, (long)E_ * E_);
  f2b(w1, w1b, (long)F_ * E_);
  f2b(w2, w2b, (long)E_ * F_);

  // QKV projection -> Qh/Kh/Vt
  gemm_nt<EPI_QKV><<<dim3(3 * E_ / 128, TOK / 128), 256, 0, stream>>>(
      srcb, wqkvb, nullptr, nullptr, Qh, Kh, Vt, b_qkv, nullptr, E_, 0);

  // fused attention
  attn_pass1<<<dim3(S_ / 128, B_ * H_), 256, 0, stream>>>(Qh, Kh, mask, rowsum);
  attn_pass2<<<dim3(S_ / 128, B_ * H_), 256, 0, stream>>>(Qh, Kh, Vt, mask,
                                                          rowsum, attnW, ctxb);

  // attn_out = ctx W_o^T + b_o + src   (residual fused)
  gemm_nt<EPI_BIAS_RES_F32><<<dim3(E_ / 128, TOK / 128), 256, 0, stream>>>(
      ctxb, wob, attn_out, nullptr, nullptr, nullptr, nullptr, b_o, src, E_, E_);

  // x1 = LN(attn_out)
  ln_kernel<<<TOK, 256, 0, stream>>>(attn_out, ln1g, ln1b, x1f, x1b);

  // h1 = relu(x1 W1^T + b1)
  gemm_nt<EPI_BIAS_RELU_BF16><<<dim3(F_ / 128, TOK / 128), 256, 0, stream>>>(
      x1b, w1b, nullptr, h1b, nullptr, nullptr, nullptr, b1, nullptr, E_, F_);

  // ffn2 = h1 W2^T + b2 + x1   (residual fused)
  gemm_nt<EPI_BIAS_RES_F32><<<dim3(E_ / 128, TOK / 128), 256, 0, stream>>>(
      h1b, w2b, ffn2, nullptr, nullptr, nullptr, nullptr, b2, x1f, F_, E_);

  // out = LN(ffn2)
  ln_kernel<<<TOK, 256, 0, stream>>>(ffn2, ln2g, ln2b, out, nullptr);
}

// Round 2
// 614.025 us; speedup vs baseline: 1.0562x; 1.0562x over previous
//
#include <hip/hip_runtime.h>
#include <cstdint>

typedef __bf16 bf16;
typedef bf16 bf16x8 __attribute__((ext_vector_type(8)));
typedef bf16 bf16x4 __attribute__((ext_vector_type(4)));
typedef float f32x4 __attribute__((ext_vector_type(4)));
typedef uint32_t u32;

static constexpr int E_ = 1024;
static constexpr int H_ = 16;
static constexpr int DH_ = 64;
static constexpr int F_ = 4096;
static constexpr int B_ = 4;
static constexpr int S_ = 1024;
static constexpr long TOK = (long)B_ * S_;  // 4096 tokens

__device__ static __forceinline__ void gld16(const void* g, void* l) {
  __builtin_amdgcn_global_load_lds(
      (const __attribute__((address_space(1))) u32*)g,
      (__attribute__((address_space(3))) u32*)l, 16, 0, 0);
}

__device__ __forceinline__ f32x4 mfma16(bf16x8 a, bf16x8 b, f32x4 c) {
  return __builtin_amdgcn_mfma_f32_16x16x32_bf16(a, b, c, 0, 0, 0);
}

// ------------------------------------------------- f32 -> bf16 (all tensors)
// One kernel, 5 regions (src, w_qkv, w_o, w1, w2), dispatch by thread index.
__global__ __launch_bounds__(256) void f2b_all(
    const float* __restrict__ s0, bf16* __restrict__ d0,
    const float* __restrict__ s1, bf16* __restrict__ d1,
    const float* __restrict__ s2, bf16* __restrict__ d2,
    const float* __restrict__ s3, bf16* __restrict__ d3,
    const float* __restrict__ s4, bf16* __restrict__ d4) {
  long v = (long)blockIdx.x * 256 + threadIdx.x;
  const float* in;
  bf16* out;
  long off;
  if (v < 524288)        { in = s0; out = d0; off = v; }
  else if (v < 917504)   { in = s1; out = d1; off = v - 524288; }
  else if (v < 1048576)  { in = s2; out = d2; off = v - 917504; }
  else if (v < 1572864)  { in = s3; out = d3; off = v - 1048576; }
  else                   { in = s4; out = d4; off = v - 1572864; }
  const float4* p = (const float4*)in + off * 2;
  float4 a = p[0], b = p[1];
  bf16x8 o = {(bf16)a.x, (bf16)a.y, (bf16)a.z, (bf16)a.w,
              (bf16)b.x, (bf16)b.y, (bf16)b.z, (bf16)b.w};
  *((bf16x8*)out + off) = o;
}

// ---------------------------------------------------------------- GEMM (NT)
// C[M,N] = A[M,K] * B[N,K]^T, bf16 inputs, m97-style global_load_lds staging.
// 128xBN tile, BK=64, 4 waves. BN=128: 2x2 waves of 64x64. BN=64: 2x2 waves
// of 64x32 (doubles grid for N=1024 GEMMs -> 2 blocks/CU instead of 1).
enum { EPI_BIAS_F32 = 0, EPI_BIAS_RELU_BF16 = 1, EPI_QKV = 2, EPI_BIAS_RES_F32 = 3 };

template <int EPI, int BN>
__global__ __launch_bounds__(256, 2) void gemm_nt(
    const bf16* __restrict__ A, const bf16* __restrict__ Bm,
    float* __restrict__ Cf, bf16* __restrict__ Cb,
    bf16* __restrict__ Qh, bf16* __restrict__ Kh, bf16* __restrict__ Vt,
    const float* __restrict__ bias, const float* __restrict__ res,
    int K, int ldc) {
  constexpr int NJ = BN / 32;  // B-fragments (cols/wave = BN/2)
  __shared__ bf16 Sm[128 * 64 + BN * 64];
  bf16* As = Sm;
  bf16* Bs = Sm + 128 * 64;
  const int tid = threadIdx.x, lane = tid & 63, wave = tid >> 6;
  const int quad = lane >> 4, l16 = lane & 15;
  const int wm = wave >> 1, wn = wave & 1;
  const int row0 = blockIdx.y * 128, col0 = blockIdx.x * BN;

  const long ldab = (long)K * 2;  // bytes per input row
  const char* Ag = (const char*)A +
                   (long)(row0 + wave * 32 + (lane >> 3)) * ldab + (lane & 7) * 16;
  const char* Bg = (const char*)Bm +
                   (long)(col0 + wave * (BN / 4) + (lane >> 3)) * ldab + (lane & 7) * 16;
  char* Al = (char*)As + (wave * 32 + (lane >> 3)) * 128 + (lane & 7) * 16;
  char* Bl = (char*)Bs + (wave * (BN / 4) + (lane >> 3)) * 128 + (lane & 7) * 16;

  f32x4 acc[4][NJ];
#pragma unroll
  for (int i = 0; i < 4; i++)
#pragma unroll
    for (int j = 0; j < NJ; j++) acc[i][j] = (f32x4){0.f, 0.f, 0.f, 0.f};

  for (int k0 = 0; k0 < K; k0 += 64) {
    __syncthreads();
#pragma unroll
    for (int c = 0; c < 4; c++) gld16(Ag + (long)c * 8 * ldab + k0 * 2, Al + c * 1024);
#pragma unroll
    for (int c = 0; c < BN / 32; c++) gld16(Bg + (long)c * 8 * ldab + k0 * 2, Bl + c * 1024);
    __syncthreads();
#pragma unroll
    for (int kk = 0; kk < 2; kk++) {
      bf16x8 af[4], bfr[NJ];
#pragma unroll
      for (int i = 0; i < 4; i++)
        af[i] = *(const bf16x8*)&As[(wm * 64 + i * 16 + l16) * 64 + kk * 32 + quad * 8];
#pragma unroll
      for (int j = 0; j < NJ; j++)
        bfr[j] = *(const bf16x8*)&Bs[(wn * (BN / 2) + j * 16 + l16) * 64 + kk * 32 + quad * 8];
#pragma unroll
      for (int i = 0; i < 4; i++)
#pragma unroll
        for (int j = 0; j < NJ; j++) acc[i][j] = mfma16(af[i], bfr[j], acc[i][j]);
    }
  }

  if constexpr (EPI == EPI_QKV) {
    // `which` is block-uniform (BN=128 divides 1024).
    const int which = col0 >> 10;
    if (which == 2) {
      // ---- V: transpose via LDS (XOR-swizzled), coalesced Vt stores. ----
      bf16* T = Sm;  // 128 cols x 128 rows = 32 KB (all of Sm, BN=128)
      __syncthreads();  // staging reads of As/Bs done
#pragma unroll
      for (int i = 0; i < 4; i++)
#pragma unroll
        for (int j = 0; j < NJ; j++)
#pragma unroll
          for (int r = 0; r < 4; r++) {
            int row_l = wm * 64 + i * 16 + quad * 4 + r;
            int col_l = wn * 64 + j * 16 + l16;
            float t = acc[i][j][r] + bias[col0 + col_l];
            T[col_l * 128 + (row_l ^ ((col_l & 7) << 4))] = (bf16)t;
          }
      __syncthreads();
      const int b_ = row0 >> 10;
      const int s0 = row0 & 1023;
#pragma unroll
      for (int g = 0; g < 8; g++) {
        int col_l = wave * 32 + g * 4 + quad;
        int nn = (col0 + col_l) & 1023;
        int h_ = nn >> 6, d_ = nn & 63;
        int sl = l16 * 8;
        bf16x8 vv = *(const bf16x8*)&T[col_l * 128 + (sl ^ ((col_l & 7) << 4))];
        *(bf16x8*)&Vt[(((long)(b_ * H_ + h_)) * DH_ + d_) * S_ + s0 + sl] = vv;
      }
    } else {
      // ---- Q/K: [bh][s][d] layout, 32B-segment coalesced. ----
#pragma unroll
      for (int i = 0; i < 4; i++)
#pragma unroll
        for (int j = 0; j < NJ; j++)
#pragma unroll
          for (int r = 0; r < 4; r++) {
            int row = row0 + wm * 64 + i * 16 + quad * 4 + r;
            int col = col0 + wn * (BN / 2) + j * 16 + l16;
            float t = acc[i][j][r] + bias[col];
            int b_ = row >> 10, s_ = row & 1023;
            int nn = col & 1023;
            int h_ = nn >> 6, d_ = nn & 63;
            long q = (((long)(b_ * H_ + h_)) * S_ + s_) * DH_ + d_;
            if (which == 0) Qh[q] = (bf16)t;
            else Kh[q] = (bf16)t;
          }
    }
  } else {
#pragma unroll
    for (int i = 0; i < 4; i++)
#pragma unroll
      for (int j = 0; j < NJ; j++)
#pragma unroll
        for (int r = 0; r < 4; r++) {
          int row = row0 + wm * 64 + i * 16 + quad * 4 + r;
          int col = col0 + wn * (BN / 2) + j * 16 + l16;
          float v = acc[i][j][r];
          if constexpr (EPI == EPI_BIAS_F32) {
            Cf[(long)row * ldc + col] = v + bias[col];
          } else if constexpr (EPI == EPI_BIAS_RES_F32) {
            Cf[(long)row * ldc + col] = v + bias[col] + res[(long)row * ldc + col];
          } else {  // EPI_BIAS_RELU_BF16
            Cb[(long)row * ldc + col] = (bf16)fmaxf(v + bias[col], 0.f);
          }
        }
  }
}

// --------------------------------------------------- fused attention, pass 1
// rowsum[bh, q] = sum_k exp(q.k*scale + mask)  (no max subtraction; scores
// are bounded ~|2.5| for this problem -> fp32-safe).
__global__ __launch_bounds__(256, 2) void attn_pass1(
    const bf16* __restrict__ Q, const bf16* __restrict__ K,
    const float* __restrict__ mask, float* __restrict__ rowsum) {
  __shared__ bf16 Qs[128 * 64];
  __shared__ bf16 Ks[128 * 64];
  const int tid = threadIdx.x, lane = tid & 63, wave = tid >> 6;
  const int quad = lane >> 4, l16 = lane & 15;
  const int q0 = blockIdx.x * 128, bh = blockIdx.y;
  const bf16* Qb = Q + ((long)bh * S_ + q0) * DH_;
  const bf16* Kb = K + (long)bh * S_ * DH_;

  {  // Q tile is contiguous 16 KB
    const char* g = (const char*)Qb + wave * 4096 + lane * 16;
    char* l = (char*)Qs + wave * 4096 + lane * 16;
#pragma unroll
    for (int c = 0; c < 4; c++) gld16(g + c * 1024, l + c * 1024);
  }

  float rs[2][4];
#pragma unroll
  for (int i = 0; i < 2; i++)
#pragma unroll
    for (int r = 0; r < 4; r++) rs[i][r] = 0.f;

  for (int t = 0; t < 8; t++) {
    __syncthreads();
    {
      const char* g = (const char*)Kb + (long)t * 16384 + wave * 4096 + lane * 16;
      char* l = (char*)Ks + wave * 4096 + lane * 16;
#pragma unroll
      for (int c = 0; c < 4; c++) gld16(g + c * 1024, l + c * 1024);
    }
    __syncthreads();
    f32x4 acc[2][8];
#pragma unroll
    for (int i = 0; i < 2; i++)
#pragma unroll
      for (int j = 0; j < 8; j++) acc[i][j] = (f32x4){0.f, 0.f, 0.f, 0.f};
#pragma unroll
    for (int kk = 0; kk < 2; kk++) {
      bf16x8 af[2], bfr[8];
#pragma unroll
      for (int i = 0; i < 2; i++)
        af[i] = *(const bf16x8*)&Qs[(wave * 32 + i * 16 + l16) * 64 + kk * 32 + quad * 8];
#pragma unroll
      for (int j = 0; j < 8; j++)
        bfr[j] = *(const bf16x8*)&Ks[(j * 16 + l16) * 64 + kk * 32 + quad * 8];
#pragma unroll
      for (int i = 0; i < 2; i++)
#pragma unroll
        for (int j = 0; j < 8; j++) acc[i][j] = mfma16(af[i], bfr[j], acc[i][j]);
    }
#pragma unroll
    for (int i = 0; i < 2; i++)
#pragma unroll
      for (int j = 0; j < 8; j++)
#pragma unroll
        for (int r = 0; r < 4; r++) {
          int qr = q0 + wave * 32 + i * 16 + quad * 4 + r;
          int gcol = t * 128 + j * 16 + l16;
          float sv = acc[i][j][r] * 0.125f + mask[(long)qr * S_ + gcol];
          rs[i][r] += __expf(sv);
        }
  }
#pragma unroll
  for (int i = 0; i < 2; i++)
#pragma unroll
    for (int r = 0; r < 4; r++) {
      float v = rs[i][r];
      v += __shfl_xor(v, 1);
      v += __shfl_xor(v, 2);
      v += __shfl_xor(v, 4);
      v += __shfl_xor(v, 8);
      if (l16 == 0)
        rowsum[(long)bh * S_ + q0 + wave * 32 + i * 16 + quad * 4 + r] = v;
    }
}

// --------------------------------------------------- fused attention, pass 2
// Recompute scores, normalize with rowsum, write W (fp32, output 1) once with
// NONTEMPORAL stores (268 MB stream, never re-read -> don't thrash L2),
// LDS round-trip P (C-layout -> A-layout), MFMA with V^T from global.
__global__ __launch_bounds__(256, 2) void attn_pass2(
    const bf16* __restrict__ Q, const bf16* __restrict__ K,
    const bf16* __restrict__ V, const float* __restrict__ mask,
    const float* __restrict__ rowsum, float* __restrict__ W,
    bf16* __restrict__ ctxb) {
  __shared__ bf16 Qs[128 * 64];
  __shared__ bf16 Ks[128 * 64];
  __shared__ bf16 Ps[128 * 136];  // +8 pad: 2-way-only read conflicts
  const int tid = threadIdx.x, lane = tid & 63, wave = tid >> 6;
  const int quad = lane >> 4, l16 = lane & 15;
  const int q0 = blockIdx.x * 128, bh = blockIdx.y;
  const bf16* Qb = Q + ((long)bh * S_ + q0) * DH_;
  const bf16* Kb = K + (long)bh * S_ * DH_;
  const bf16* Vb = V + (long)bh * DH_ * S_;

  float rinv[2][4];
#pragma unroll
  for (int i = 0; i < 2; i++)
#pragma unroll
    for (int r = 0; r < 4; r++)
      rinv[i][r] =
          1.0f / rowsum[(long)bh * S_ + q0 + wave * 32 + i * 16 + quad * 4 + r];

  {
    const char* g = (const char*)Qb + wave * 4096 + lane * 16;
    char* l = (char*)Qs + wave * 4096 + lane * 16;
#pragma unroll
    for (int c = 0; c < 4; c++) gld16(g + c * 1024, l + c * 1024);
  }

  f32x4 cacc[2][4];
#pragma unroll
  for (int i = 0; i < 2; i++)
#pragma unroll
    for (int j = 0; j < 4; j++) cacc[i][j] = (f32x4){0.f, 0.f, 0.f, 0.f};

  for (int t = 0; t < 8; t++) {
    __syncthreads();
    {
      const char* g = (const char*)Kb + (long)t * 16384 + wave * 4096 + lane * 16;
      char* l = (char*)Ks + wave * 4096 + lane * 16;
#pragma unroll
      for (int c = 0; c < 4; c++) gld16(g + c * 1024, l + c * 1024);
    }
    __syncthreads();
    f32x4 acc[2][8];
#pragma unroll
    for (int i = 0; i < 2; i++)
#pragma unroll
      for (int j = 0; j < 8; j++) acc[i][j] = (f32x4){0.f, 0.f, 0.f, 0.f};
#pragma unroll
    for (int kk = 0; kk < 2; kk++) {
      bf16x8 af[2], bfr[8];
#pragma unroll
      for (int i = 0; i < 2; i++)
        af[i] = *(const bf16x8*)&Qs[(wave * 32 + i * 16 + l16) * 64 + kk * 32 + quad * 8];
#pragma unroll
      for (int j = 0; j < 8; j++)
        bfr[j] = *(const bf16x8*)&Ks[(j * 16 + l16) * 64 + kk * 32 + quad * 8];
#pragma unroll
      for (int i = 0; i < 2; i++)
#pragma unroll
        for (int j = 0; j < 8; j++) acc[i][j] = mfma16(af[i], bfr[j], acc[i][j]);
    }
    // exp, normalize, emit W + P
#pragma unroll
    for (int i = 0; i < 2; i++)
#pragma unroll
      for (int j = 0; j < 8; j++)
#pragma unroll
        for (int r = 0; r < 4; r++) {
          int ql = wave * 32 + i * 16 + quad * 4 + r;
          int qr = q0 + ql;
          int col = j * 16 + l16, gcol = t * 128 + col;
          float u = __expf(acc[i][j][r] * 0.125f + mask[(long)qr * S_ + gcol]) *
                    rinv[i][r];
          __builtin_nontemporal_store(u, &W[((long)bh * S_ + qr) * S_ + gcol]);
          Ps[ql * 136 + col] = (bf16)u;
        }
    __syncthreads();  // P visible (cross-lane within wave; be safe)
    // PV: ctx += P(128xk128) * Vt(64xk128)^T
#pragma unroll
    for (int kk = 0; kk < 4; kk++) {
      bf16x8 pf[2], vf[4];
#pragma unroll
      for (int i = 0; i < 2; i++)
        pf[i] = *(const bf16x8*)&Ps[(wave * 32 + i * 16 + l16) * 136 + kk * 32 + quad * 8];
#pragma unroll
      for (int j = 0; j < 4; j++)
        vf[j] = *(const bf16x8*)(Vb + (long)(j * 16 + l16) * S_ + t * 128 +
                                 kk * 32 + quad * 8);
#pragma unroll
      for (int i = 0; i < 2; i++)
#pragma unroll
        for (int j = 0; j < 4; j++) cacc[i][j] = mfma16(pf[i], vf[j], cacc[i][j]);
    }
  }
  const int b_ = bh >> 4, h_ = bh & 15;
#pragma unroll
  for (int i = 0; i < 2; i++)
#pragma unroll
    for (int j = 0; j < 4; j++)
#pragma unroll
      for (int r = 0; r < 4; r++) {
        int qr = q0 + wave * 32 + i * 16 + quad * 4 + r;
        ctxb[((long)b_ * S_ + qr) * E_ + h_ * 64 + j * 16 + l16] =
            (bf16)cacc[i][j][r];
      }
}

// ------------------------------------------------------- layernorm (single in)
// Residual add is fused into the producing GEMM's epilogue (EPI_BIAS_RES_F32),
// so this reads ONE fp32 stream.
__global__ __launch_bounds__(256) void ln_kernel(
    const float* __restrict__ a, const float* __restrict__ g,
    const float* __restrict__ beta, float* __restrict__ outf,
    bf16* __restrict__ outb) {
  const int tid = threadIdx.x;
  const int wave = tid >> 6, lane = tid & 63;
  long base = (long)blockIdx.x * E_ + tid * 4;
  float4 x = *(const float4*)(a + base);
  float s = x.x + x.y + x.z + x.w;
  float sq = x.x * x.x + x.y * x.y + x.z * x.z + x.w * x.w;
#pragma unroll
  for (int o = 32; o; o >>= 1) { s += __shfl_xor(s, o); sq += __shfl_xor(sq, o); }
  __shared__ float rs[4], rq[4];
  if (!lane) { rs[wave] = s; rq[wave] = sq; }
  __syncthreads();
  s = rs[0] + rs[1] + rs[2] + rs[3];
  sq = rq[0] + rq[1] + rq[2] + rq[3];
  float mu = s * (1.f / E_);
  float var = sq * (1.f / E_) - mu * mu;
  float rstd = rsqrtf(var + 1e-5f);
  int c = tid * 4;
  float4 gg = *(const float4*)(g + c);
  float4 bb = *(const float4*)(beta + c);
  float o0 = (x.x - mu) * rstd * gg.x + bb.x;
  float o1 = (x.y - mu) * rstd * gg.y + bb.y;
  float o2 = (x.z - mu) * rstd * gg.z + bb.z;
  float o3 = (x.w - mu) * rstd * gg.w + bb.w;
  if (outf) *(float4*)(outf + base) = make_float4(o0, o1, o2, o3);
  if (outb) {
    bf16x4 ob = {(bf16)o0, (bf16)o1, (bf16)o2, (bf16)o3};
    *(bf16x4*)(outb + base) = ob;
  }
}

// ---------------------------------------------------------------- launch
extern "C" void kernel_launch(void* const* d_in, const int* in_sizes, int n_in,
                              void* d_out, int out_size, void* d_ws, size_t ws_size,
                              hipStream_t stream) {
  const float* src   = (const float*)d_in[0];
  const float* mask  = (const float*)d_in[1];
  const float* w_qkv = (const float*)d_in[2];
  const float* b_qkv = (const float*)d_in[3];
  const float* w_o   = (const float*)d_in[4];
  const float* b_o   = (const float*)d_in[5];
  const float* w1    = (const float*)d_in[6];
  const float* b1    = (const float*)d_in[7];
  const float* w2    = (const float*)d_in[8];
  const float* b2    = (const float*)d_in[9];
  const float* ln1g  = (const float*)d_in[10];
  const float* ln1b  = (const float*)d_in[11];
  const float* ln2g  = (const float*)d_in[12];
  const float* ln2b  = (const float*)d_in[13];

  float* out = (float*)d_out;
  float* attnW = out + TOK * E_;  // [B,H,S,S] fp32 (output 1)

  char* w = (char*)d_ws;
  auto alloc = [&](size_t bytes) {
    void* p = w;
    w += (bytes + 255) & ~(size_t)255;
    return p;
  };
  bf16* srcb  = (bf16*)alloc(TOK * E_ * 2);
  bf16* wqkvb = (bf16*)alloc((size_t)3 * E_ * E_ * 2);
  bf16* wob   = (bf16*)alloc((size_t)E_ * E_ * 2);
  bf16* w1b   = (bf16*)alloc((size_t)F_ * E_ * 2);
  bf16* w2b   = (bf16*)alloc((size_t)E_ * F_ * 2);
  bf16* Qh    = (bf16*)alloc((size_t)B_ * H_ * S_ * DH_ * 2);
  bf16* Kh    = (bf16*)alloc((size_t)B_ * H_ * S_ * DH_ * 2);
  bf16* Vt    = (bf16*)alloc((size_t)B_ * H_ * DH_ * S_ * 2);
  bf16* ctxb  = (bf16*)alloc(TOK * E_ * 2);
  float* attn_out = (float*)alloc(TOK * E_ * 4);
  float* x1f  = (float*)alloc(TOK * E_ * 4);
  bf16* x1b   = (bf16*)alloc(TOK * E_ * 2);
  bf16* h1b   = (bf16*)alloc(TOK * (size_t)F_ * 2);
  float* ffn2 = (float*)alloc(TOK * E_ * 4);
  float* rowsum = (float*)alloc((size_t)B_ * H_ * S_ * 4);

  // all f32->bf16 conversions in one launch (2097152 vec8 units / 256)
  f2b_all<<<8192, 256, 0, stream>>>(src, srcb, w_qkv, wqkvb, w_o, wob,
                                    w1, w1b, w2, w2b);

  // QKV projection -> Qh/Kh/Vt
  gemm_nt<EPI_QKV, 128><<<dim3(3 * E_ / 128, TOK / 128), 256, 0, stream>>>(
      srcb, wqkvb, nullptr, nullptr, Qh, Kh, Vt, b_qkv, nullptr, E_, 0);

  // fused attention
  attn_pass1<<<dim3(S_ / 128, B_ * H_), 256, 0, stream>>>(Qh, Kh, mask, rowsum);
  attn_pass2<<<dim3(S_ / 128, B_ * H_), 256, 0, stream>>>(Qh, Kh, Vt, mask,
                                                          rowsum, attnW, ctxb);

  // attn_out = ctx W_o^T + b_o + src   (residual fused; BN=64 -> 512 blocks)
  gemm_nt<EPI_BIAS_RES_F32, 64><<<dim3(E_ / 64, TOK / 128), 256, 0, stream>>>(
      ctxb, wob, attn_out, nullptr, nullptr, nullptr, nullptr, b_o, src, E_, E_);

  // x1 = LN(attn_out)
  ln_kernel<<<TOK, 256, 0, stream>>>(attn_out, ln1g, ln1b, x1f, x1b);

  // h1 = relu(x1 W1^T + b1)
  gemm_nt<EPI_BIAS_RELU_BF16, 128><<<dim3(F_ / 128, TOK / 128), 256, 0, stream>>>(
      x1b, w1b, nullptr, h1b, nullptr, nullptr, nullptr, b1, nullptr, E_, F_);

  // ffn2 = h1 W2^T + b2 + x1   (residual fused; BN=64 -> 512 blocks)
  gemm_nt<EPI_BIAS_RES_F32, 64><<<dim3(E_ / 64, TOK / 128), 256, 0, stream>>>(
      h1b, w2b, ffn2, nullptr, nullptr, nullptr, nullptr, b2, x1f, F_, E_);

  // out = LN(ffn2)
  ln_kernel<<<TOK, 256, 0, stream>>>(ffn2, ln2g, ln2b, out, nullptr);
}